// Round 11
// baseline (198.939 us; speedup 1.0000x reference)
//
#include <hip/hip_runtime.h>
#include <math.h>

#define BB 16
#define KK 5
#define NN 4096
#define DD 1024
#define TOPK 9
#define EPSV 1e-12f
#define RPB 64           // patch rows per block
#define NBLK (NN / RPB)  // 64 blocks per batch

typedef float f32x4 __attribute__((ext_vector_type(4)));

// ---- DPP wave64 reductions (VALU pipe) ----
#define DPP_ADD_F32(x, CTRL)                                                   \
  do {                                                                         \
    int _s = __builtin_amdgcn_update_dpp(0, __float_as_int(x), CTRL, 0xf, 0xf, \
                                         true);                                \
    x += __int_as_float(_s);                                                   \
  } while (0)

__device__ __forceinline__ float wave_sum63(float x) {
  DPP_ADD_F32(x, 0x111);  // row_shr:1
  DPP_ADD_F32(x, 0x112);  // row_shr:2
  DPP_ADD_F32(x, 0x114);  // row_shr:4
  DPP_ADD_F32(x, 0x118);  // row_shr:8
  DPP_ADD_F32(x, 0x142);  // row_bcast:15
  DPP_ADD_F32(x, 0x143);  // row_bcast:31
  return x;  // lane 63 holds the wave sum
}

template <int CTRL>
__device__ __forceinline__ unsigned long long dpp_max_u64_step(
    unsigned long long k) {
  unsigned lo = (unsigned)__builtin_amdgcn_update_dpp(
      0, (int)(unsigned)k, CTRL, 0xf, 0xf, true);
  unsigned hi = (unsigned)__builtin_amdgcn_update_dpp(
      0, (int)(unsigned)(k >> 32), CTRL, 0xf, 0xf, true);
  unsigned long long o = ((unsigned long long)hi << 32) | lo;
  return o > k ? o : k;
}

__device__ __forceinline__ unsigned long long wave_max_u64(
    unsigned long long k) {
  k = dpp_max_u64_step<0x111>(k);
  k = dpp_max_u64_step<0x112>(k);
  k = dpp_max_u64_step<0x114>(k);
  k = dpp_max_u64_step<0x118>(k);
  k = dpp_max_u64_step<0x142>(k);
  k = dpp_max_u64_step<0x143>(k);
  unsigned mlo = (unsigned)__builtin_amdgcn_readlane((int)(unsigned)k, 63);
  unsigned mhi =
      (unsigned)__builtin_amdgcn_readlane((int)(unsigned)(k >> 32), 63);
  return ((unsigned long long)mhi << 32) | mlo;
}

// pack (sim, row) into an order-preserving u64 key; tie-break: smaller row
__device__ __forceinline__ unsigned long long pack_key(float v, int row) {
  unsigned u = __float_as_uint(v);
  u = (u & 0x80000000u) ? ~u : (u | 0x80000000u);
  return ((unsigned long long)u << 32) | (unsigned)(~row);
}

// ---------------- fused kernel: sims + per-block top-9 + closer merge ----
// grid = (NBLK, B), 256 threads = 4 waves. R8/R10 streaming structure.
// The last block of each batch to finish (device-scope counter) merges the
// 64x9 candidates per cue and writes the gathered means -> no 2nd kernel.
__global__ __launch_bounds__(256, 4) void fused_kernel(
    const float* __restrict__ patches, const float* __restrict__ cue,
    unsigned long long* __restrict__ cand, float* __restrict__ invn,
    int* __restrict__ cnt, float* __restrict__ out) {
  int b = blockIdx.y;
  int row0 = blockIdx.x * RPB;
  int wid = threadIdx.x >> 6;
  int lane = threadIdx.x & 63;

  __shared__ float cue_lds[KK * DD];            // 20 KB normalized cues
  __shared__ unsigned long long keyl[KK][RPB];  // 2.5 KB per-row keys

  const f32x4* pb = (const f32x4*)(patches + (size_t)b * NN * DD);

  // prologue: issue row-0 loads immediately (don't wait for cue norm)
  const f32x4* pc = pb + (size_t)(row0 + wid) * 256;
  f32x4 cur0 = pc[lane], cur1 = pc[64 + lane], cur2 = pc[128 + lane],
        cur3 = pc[192 + lane];

  // cooperative cue normalize: wave w handles k = w, w+4 (wave0 gets k=4)
  for (int k = wid; k < KK; k += 4) {
    const f32x4* cb = (const f32x4*)(cue + ((size_t)b * KK + k) * DD);
    f32x4 v[4];
#pragma unroll
    for (int j = 0; j < 4; ++j) v[j] = cb[j * 64 + lane];
    float s = 0.f;
#pragma unroll
    for (int j = 0; j < 4; ++j)
      s += v[j].x * v[j].x + v[j].y * v[j].y + v[j].z * v[j].z +
           v[j].w * v[j].w;
    s = wave_sum63(s);
    s = __int_as_float(__builtin_amdgcn_readlane(__float_as_int(s), 63));
    float inv = 1.0f / fmaxf(sqrtf(s), EPSV);
#pragma unroll
    for (int j = 0; j < 4; ++j) {
      f32x4 o;
      o.x = v[j].x * inv; o.y = v[j].y * inv;
      o.z = v[j].z * inv; o.w = v[j].w * inv;
      *(f32x4*)&cue_lds[k * DD + j * 256 + lane * 4] = o;
    }
  }
  __syncthreads();

#pragma unroll 2
  for (int i = 0; i < RPB / 4; ++i) {
    int r = wid + 4 * i;   // row within block
    int row = row0 + r;    // row within batch
    // prefetch next row (last iter re-loads current: harmless L2 hit)
    int rn = (i < RPB / 4 - 1) ? (r + 4) : r;
    const f32x4* pn = pb + (size_t)(row0 + rn) * 256;
    f32x4 n0 = pn[lane], n1 = pn[64 + lane], n2 = pn[128 + lane],
          n3 = pn[192 + lane];

    float acc0 = 0.f, acc1 = 0.f, acc2 = 0.f, acc3 = 0.f, acc4 = 0.f;
    float nr = 0.f;
#pragma unroll
    for (int j = 0; j < 4; ++j) {
      f32x4 p = (j == 0) ? cur0 : (j == 1) ? cur1 : (j == 2) ? cur2 : cur3;
      nr += p.x * p.x + p.y * p.y + p.z * p.z + p.w * p.w;
      const float* cl = &cue_lds[j * 256 + lane * 4];
      f32x4 c0 = *(const f32x4*)(cl + 0 * DD);
      f32x4 c1 = *(const f32x4*)(cl + 1 * DD);
      f32x4 c2 = *(const f32x4*)(cl + 2 * DD);
      f32x4 c3 = *(const f32x4*)(cl + 3 * DD);
      f32x4 c4 = *(const f32x4*)(cl + 4 * DD);
      acc0 += p.x * c0.x + p.y * c0.y + p.z * c0.z + p.w * c0.w;
      acc1 += p.x * c1.x + p.y * c1.y + p.z * c1.z + p.w * c1.w;
      acc2 += p.x * c2.x + p.y * c2.y + p.z * c2.z + p.w * c2.w;
      acc3 += p.x * c3.x + p.y * c3.y + p.z * c3.z + p.w * c3.w;
      acc4 += p.x * c4.x + p.y * c4.y + p.z * c4.z + p.w * c4.w;
    }
    nr = wave_sum63(nr);
    acc0 = wave_sum63(acc0);
    acc1 = wave_sum63(acc1);
    acc2 = wave_sum63(acc2);
    acc3 = wave_sum63(acc3);
    acc4 = wave_sum63(acc4);
    if (lane == 63) {
      float inv = 1.0f / fmaxf(sqrtf(nr), EPSV);
      invn[b * NN + row] = inv;
      keyl[0][r] = pack_key(acc0 * inv, row);
      keyl[1][r] = pack_key(acc1 * inv, row);
      keyl[2][r] = pack_key(acc2 * inv, row);
      keyl[3][r] = pack_key(acc3 * inv, row);
      keyl[4][r] = pack_key(acc4 * inv, row);
    }
    cur0 = n0; cur1 = n1; cur2 = n2; cur3 = n3;
  }
  __syncthreads();

  // per-block top-9 per cue: wave w handles cue w (wave 0 also cue 4)
  for (int k = wid; k < KK; k += 4) {
    unsigned long long key = keyl[k][lane];
    unsigned long long* dst =
        cand + (((size_t)b * KK + k) * NBLK + blockIdx.x) * TOPK;
#pragma unroll
    for (int it = 0; it < TOPK; ++it) {
      unsigned long long m = wave_max_u64(key);
      if (lane == 0) dst[it] = m;
      if (key == m) key = 0ull;
    }
  }

  // ---- closer election: last block of batch b merges + gathers ----
  __threadfence();  // release: make cand/invn visible device-wide
  __shared__ int closer;
  if (threadIdx.x == 0) closer = (atomicAdd(&cnt[b], 1) == NBLK - 1);
  __syncthreads();
  if (!closer) return;
  __threadfence();  // acquire: invalidate caches before reading cand/invn

  for (int k = wid; k < KK; k += 4) {
    // merge 64x9 candidate keys -> global top-9 (9 keys per lane)
    unsigned long long kk2[TOPK];
    const unsigned long long* cb2 =
        cand + ((size_t)b * KK + k) * (NBLK * TOPK);
#pragma unroll
    for (int j = 0; j < TOPK; ++j) kk2[j] = cb2[j * 64 + lane];
    int selr[TOPK];
    float seli[TOPK];
#pragma unroll
    for (int it = 0; it < TOPK; ++it) {
      unsigned long long m = kk2[0];
#pragma unroll
      for (int j = 1; j < TOPK; ++j) m = kk2[j] > m ? kk2[j] : m;
      m = wave_max_u64(m);
      selr[it] = (int)(~(unsigned)(m & 0xFFFFFFFFu));
      seli[it] = invn[b * NN + selr[it]];
#pragma unroll
      for (int j = 0; j < TOPK; ++j)
        if (kk2[j] == m) kk2[j] = 0ull;
    }
    // gather-mean: 9 rows x 1024 floats; lane covers 4 f32x4 chunks
    f32x4 a0 = 0.f, a1 = 0.f, a2 = 0.f, a3 = 0.f;
#pragma unroll
    for (int it = 0; it < TOPK; ++it) {
      const f32x4* pr = pb + (size_t)selr[it] * 256;
      float iv = seli[it];
      a0 += pr[lane] * iv;
      a1 += pr[64 + lane] * iv;
      a2 += pr[128 + lane] * iv;
      a3 += pr[192 + lane] * iv;
    }
    const float inv9 = 1.0f / 9.0f;
    f32x4* orow = (f32x4*)(out + ((size_t)b * KK + k) * DD);
    orow[lane] = a0 * inv9;
    orow[64 + lane] = a1 * inv9;
    orow[128 + lane] = a2 * inv9;
    orow[192 + lane] = a3 * inv9;
  }
}

extern "C" void kernel_launch(void* const* d_in, const int* in_sizes, int n_in,
                              void* d_out, int out_size, void* d_ws, size_t ws_size,
                              hipStream_t stream) {
  const float* cue = (const float*)d_in[0];      // (B, K, D) f32
  const float* patches = (const float*)d_in[1];  // (B, N, D) f32
  float* out = (float*)d_out;                    // (B, K, D) f32

  // workspace: invn (256 KB) | cand (368.64 KB) | cnt (64 B)
  float* invn = (float*)d_ws;
  unsigned long long* cand =
      (unsigned long long*)((char*)d_ws + (size_t)BB * NN * 4);
  int* cnt = (int*)((char*)d_ws + (size_t)BB * NN * 4 +
                    (size_t)BB * KK * NBLK * TOPK * 8);

  hipMemsetAsync(cnt, 0, BB * sizeof(int), stream);
  dim3 g(NBLK, BB);
  fused_kernel<<<g, 256, 0, stream>>>(patches, cue, cand, invn, cnt, out);
}

// Round 12
// 56.873 us; speedup vs baseline: 3.4979x; 3.4979x over previous
//
#include <hip/hip_runtime.h>
#include <math.h>

#define BB 16
#define KK 5
#define NN 4096
#define DD 1024
#define TOPK 9
#define EPSV 1e-12f
#define RPB 32           // patch rows per block (2048 blocks = 8/CU)
#define NBLK (NN / RPB)  // 128 blocks per batch

typedef float f32x4 __attribute__((ext_vector_type(4)));

// ---- DPP wave64 reductions (VALU pipe) ----
#define DPP_ADD_F32(x, CTRL)                                                   \
  do {                                                                         \
    int _s = __builtin_amdgcn_update_dpp(0, __float_as_int(x), CTRL, 0xf, 0xf, \
                                         true);                                \
    x += __int_as_float(_s);                                                   \
  } while (0)

__device__ __forceinline__ float wave_sum63(float x) {
  DPP_ADD_F32(x, 0x111);  // row_shr:1
  DPP_ADD_F32(x, 0x112);  // row_shr:2
  DPP_ADD_F32(x, 0x114);  // row_shr:4
  DPP_ADD_F32(x, 0x118);  // row_shr:8
  DPP_ADD_F32(x, 0x142);  // row_bcast:15
  DPP_ADD_F32(x, 0x143);  // row_bcast:31
  return x;  // lane 63 holds the wave sum
}

template <int CTRL>
__device__ __forceinline__ unsigned long long dpp_max_u64_step(
    unsigned long long k) {
  unsigned lo = (unsigned)__builtin_amdgcn_update_dpp(
      0, (int)(unsigned)k, CTRL, 0xf, 0xf, true);
  unsigned hi = (unsigned)__builtin_amdgcn_update_dpp(
      0, (int)(unsigned)(k >> 32), CTRL, 0xf, 0xf, true);
  unsigned long long o = ((unsigned long long)hi << 32) | lo;
  return o > k ? o : k;
}

__device__ __forceinline__ unsigned long long wave_max_u64(
    unsigned long long k) {
  k = dpp_max_u64_step<0x111>(k);
  k = dpp_max_u64_step<0x112>(k);
  k = dpp_max_u64_step<0x114>(k);
  k = dpp_max_u64_step<0x118>(k);
  k = dpp_max_u64_step<0x142>(k);
  k = dpp_max_u64_step<0x143>(k);
  unsigned mlo = (unsigned)__builtin_amdgcn_readlane((int)(unsigned)k, 63);
  unsigned mhi =
      (unsigned)__builtin_amdgcn_readlane((int)(unsigned)(k >> 32), 63);
  return ((unsigned long long)mhi << 32) | mlo;
}

// pack (sim, row) into an order-preserving u64 key; tie-break: smaller row
__device__ __forceinline__ unsigned long long pack_key(float v, int row) {
  unsigned u = __float_as_uint(v);
  u = (u & 0x80000000u) ? ~u : (u | 0x80000000u);
  return ((unsigned long long)u << 32) | (unsigned)(~row);
}

// ---------------- kernel A: cue-norm + sims + invn + per-block top-9 -------
// grid = (NBLK, B) = 2048 blocks, 256 threads = 4 waves, 64 VGPR (measured
// R11) -> 8 blocks/CU co-resident at launch_bounds(256,8): 2x the in-flight
// loads of the 1024-block variant.
__global__ __launch_bounds__(256, 8) void sims_kernel(
    const float* __restrict__ patches, const float* __restrict__ cue,
    unsigned long long* __restrict__ cand, float* __restrict__ invn) {
  int b = blockIdx.y;
  int row0 = blockIdx.x * RPB;
  int wid = threadIdx.x >> 6;
  int lane = threadIdx.x & 63;

  __shared__ float cue_lds[KK * DD];            // 20 KB normalized cues
  __shared__ unsigned long long keyl[KK][RPB];  // 1.25 KB per-row keys

  const f32x4* pb = (const f32x4*)(patches + (size_t)b * NN * DD);

  // prologue: issue row-0 loads immediately (don't wait for cue norm)
  const f32x4* pc = pb + (size_t)(row0 + wid) * 256;
  f32x4 cur0 = pc[lane], cur1 = pc[64 + lane], cur2 = pc[128 + lane],
        cur3 = pc[192 + lane];

  // cooperative cue normalize: wave w handles k = w, w+4 (wave0 gets k=4)
  for (int k = wid; k < KK; k += 4) {
    const f32x4* cb = (const f32x4*)(cue + ((size_t)b * KK + k) * DD);
    f32x4 v[4];
#pragma unroll
    for (int j = 0; j < 4; ++j) v[j] = cb[j * 64 + lane];
    float s = 0.f;
#pragma unroll
    for (int j = 0; j < 4; ++j)
      s += v[j].x * v[j].x + v[j].y * v[j].y + v[j].z * v[j].z +
           v[j].w * v[j].w;
    s = wave_sum63(s);
    s = __int_as_float(__builtin_amdgcn_readlane(__float_as_int(s), 63));
    float inv = 1.0f / fmaxf(sqrtf(s), EPSV);
#pragma unroll
    for (int j = 0; j < 4; ++j) {
      f32x4 o;
      o.x = v[j].x * inv; o.y = v[j].y * inv;
      o.z = v[j].z * inv; o.w = v[j].w * inv;
      *(f32x4*)&cue_lds[k * DD + j * 256 + lane * 4] = o;
    }
  }
  __syncthreads();

#pragma unroll 2
  for (int i = 0; i < RPB / 4; ++i) {
    int r = wid + 4 * i;   // row within block
    int row = row0 + r;    // row within batch
    // prefetch next row (last iter re-loads current: harmless L2 hit)
    int rn = (i < RPB / 4 - 1) ? (r + 4) : r;
    const f32x4* pn = pb + (size_t)(row0 + rn) * 256;
    f32x4 n0 = pn[lane], n1 = pn[64 + lane], n2 = pn[128 + lane],
          n3 = pn[192 + lane];

    float acc0 = 0.f, acc1 = 0.f, acc2 = 0.f, acc3 = 0.f, acc4 = 0.f;
    float nr = 0.f;
#pragma unroll
    for (int j = 0; j < 4; ++j) {
      f32x4 p = (j == 0) ? cur0 : (j == 1) ? cur1 : (j == 2) ? cur2 : cur3;
      nr += p.x * p.x + p.y * p.y + p.z * p.z + p.w * p.w;
      const float* cl = &cue_lds[j * 256 + lane * 4];
      f32x4 c0 = *(const f32x4*)(cl + 0 * DD);
      f32x4 c1 = *(const f32x4*)(cl + 1 * DD);
      f32x4 c2 = *(const f32x4*)(cl + 2 * DD);
      f32x4 c3 = *(const f32x4*)(cl + 3 * DD);
      f32x4 c4 = *(const f32x4*)(cl + 4 * DD);
      acc0 += p.x * c0.x + p.y * c0.y + p.z * c0.z + p.w * c0.w;
      acc1 += p.x * c1.x + p.y * c1.y + p.z * c1.z + p.w * c1.w;
      acc2 += p.x * c2.x + p.y * c2.y + p.z * c2.z + p.w * c2.w;
      acc3 += p.x * c3.x + p.y * c3.y + p.z * c3.z + p.w * c3.w;
      acc4 += p.x * c4.x + p.y * c4.y + p.z * c4.z + p.w * c4.w;
    }
    nr = wave_sum63(nr);
    acc0 = wave_sum63(acc0);
    acc1 = wave_sum63(acc1);
    acc2 = wave_sum63(acc2);
    acc3 = wave_sum63(acc3);
    acc4 = wave_sum63(acc4);
    if (lane == 63) {
      float inv = 1.0f / fmaxf(sqrtf(nr), EPSV);
      invn[b * NN + row] = inv;
      keyl[0][r] = pack_key(acc0 * inv, row);
      keyl[1][r] = pack_key(acc1 * inv, row);
      keyl[2][r] = pack_key(acc2 * inv, row);
      keyl[3][r] = pack_key(acc3 * inv, row);
      keyl[4][r] = pack_key(acc4 * inv, row);
    }
    cur0 = n0; cur1 = n1; cur2 = n2; cur3 = n3;
  }
  __syncthreads();

  // per-block top-9 per cue: wave w handles cue w (wave 0 also cue 4).
  // RPB=32 keys live in lanes 0-31; other lanes carry the 0 identity.
  for (int k = wid; k < KK; k += 4) {
    unsigned long long key = (lane < RPB) ? keyl[k][lane] : 0ull;
    unsigned long long* dst =
        cand + (((size_t)b * KK + k) * NBLK + blockIdx.x) * TOPK;
#pragma unroll
    for (int it = 0; it < TOPK; ++it) {
      unsigned long long m = wave_max_u64(key);
      if (lane == 0) dst[it] = m;
      if (key == m) key = 0ull;
    }
  }
}

// ---------------- kernel B: merge 128x9 candidates + gather-mean ----------
// grid = B*K blocks, 256 threads. Wave 0 merges 1152 candidate keys
// (18/lane) -> global top-9; then all 4 waves gather the 9 patch rows.
__global__ __launch_bounds__(256) void topk_gather_kernel(
    const float* __restrict__ patches, const unsigned long long* __restrict__ cand,
    const float* __restrict__ invn, float* __restrict__ out) {
  int bk = blockIdx.x;  // 0..B*K
  int b = bk / KK;
  int wid = threadIdx.x >> 6, lane = threadIdx.x & 63;

  __shared__ int sel_idx[TOPK];
  __shared__ float sel_inv[TOPK];

  if (wid == 0) {
    const int NC = NBLK * TOPK / 64;  // 18 keys per lane
    unsigned long long kk[NC];
    const unsigned long long* cb = cand + (size_t)bk * NBLK * TOPK;
#pragma unroll
    for (int j = 0; j < NC; ++j) kk[j] = cb[j * 64 + lane];
#pragma unroll
    for (int it = 0; it < TOPK; ++it) {
      unsigned long long m = kk[0];
#pragma unroll
      for (int j = 1; j < NC; ++j) m = kk[j] > m ? kk[j] : m;
      m = wave_max_u64(m);
      if (lane == 0) {
        int idx = (int)(~(unsigned)(m & 0xFFFFFFFFu));
        sel_idx[it] = idx;
        sel_inv[it] = invn[b * NN + idx];
      }
#pragma unroll
      for (int j = 0; j < NC; ++j)
        if (kk[j] == m) kk[j] = 0ull;
    }
  }
  __syncthreads();

  const float4* pb = (const float4*)(patches + (size_t)b * NN * DD);
  float4 acc; acc.x = acc.y = acc.z = acc.w = 0.f;
#pragma unroll
  for (int it = 0; it < TOPK; ++it) {
    float inv = sel_inv[it];
    float4 p = pb[(size_t)sel_idx[it] * 256 + threadIdx.x];
    acc.x += p.x * inv; acc.y += p.y * inv;
    acc.z += p.z * inv; acc.w += p.w * inv;
  }
  const float inv9 = 1.0f / 9.0f;
  float4 o;
  o.x = acc.x * inv9; o.y = acc.y * inv9;
  o.z = acc.z * inv9; o.w = acc.w * inv9;
  ((float4*)(out + (size_t)bk * DD))[threadIdx.x] = o;
}

extern "C" void kernel_launch(void* const* d_in, const int* in_sizes, int n_in,
                              void* d_out, int out_size, void* d_ws, size_t ws_size,
                              hipStream_t stream) {
  const float* cue = (const float*)d_in[0];      // (B, K, D) f32
  const float* patches = (const float*)d_in[1];  // (B, N, D) f32
  float* out = (float*)d_out;                    // (B, K, D) f32

  // workspace: invn (B*N f32 = 256 KB) | cand (B*K*128*9 u64 = 737 KB)
  float* invn = (float*)d_ws;
  unsigned long long* cand =
      (unsigned long long*)((char*)d_ws + (size_t)BB * NN * 4);

  dim3 g2(NBLK, BB);
  sims_kernel<<<g2, 256, 0, stream>>>(patches, cue, cand, invn);
  topk_gather_kernel<<<BB * KK, 256, 0, stream>>>(patches, cand, invn, out);
}

// Round 13
// 54.862 us; speedup vs baseline: 3.6262x; 1.0367x over previous
//
#include <hip/hip_runtime.h>
#include <math.h>

#define BB 16
#define KK 5
#define NN 4096
#define DD 1024
#define TOPK 9
#define EPSV 1e-12f
#define RPB 64   // patch rows per block in sims kernel

typedef float f32x4 __attribute__((ext_vector_type(4)));
typedef float f32x2 __attribute__((ext_vector_type(2)));

// packed f32 FMA (VOP3P): d[i] = a[i]*b[i] + c[i], 2 FMAs per issue slot
__device__ __forceinline__ f32x2 pk_fma(f32x2 a, f32x2 b, f32x2 c) {
  f32x2 d;
  asm("v_pk_fma_f32 %0, %1, %2, %3" : "=v"(d) : "v"(a), "v"(b), "v"(c));
  return d;
}

// ---- DPP wave64 reductions (VALU pipe) ----
#define DPP_ADD_F32(x, CTRL)                                                   \
  do {                                                                         \
    int _s = __builtin_amdgcn_update_dpp(0, __float_as_int(x), CTRL, 0xf, 0xf, \
                                         true);                                \
    x += __int_as_float(_s);                                                   \
  } while (0)

__device__ __forceinline__ float wave_sum63(float x) {
  DPP_ADD_F32(x, 0x111);  // row_shr:1
  DPP_ADD_F32(x, 0x112);  // row_shr:2
  DPP_ADD_F32(x, 0x114);  // row_shr:4
  DPP_ADD_F32(x, 0x118);  // row_shr:8
  DPP_ADD_F32(x, 0x142);  // row_bcast:15
  DPP_ADD_F32(x, 0x143);  // row_bcast:31
  return x;  // lane 63 holds the wave sum
}

template <int CTRL>
__device__ __forceinline__ unsigned long long dpp_max_u64_step(
    unsigned long long k) {
  unsigned lo = (unsigned)__builtin_amdgcn_update_dpp(
      0, (int)(unsigned)k, CTRL, 0xf, 0xf, true);
  unsigned hi = (unsigned)__builtin_amdgcn_update_dpp(
      0, (int)(unsigned)(k >> 32), CTRL, 0xf, 0xf, true);
  unsigned long long o = ((unsigned long long)hi << 32) | lo;
  return o > k ? o : k;
}

__device__ __forceinline__ unsigned long long wave_max_u64(
    unsigned long long k) {
  k = dpp_max_u64_step<0x111>(k);
  k = dpp_max_u64_step<0x112>(k);
  k = dpp_max_u64_step<0x114>(k);
  k = dpp_max_u64_step<0x118>(k);
  k = dpp_max_u64_step<0x142>(k);
  k = dpp_max_u64_step<0x143>(k);
  unsigned mlo = (unsigned)__builtin_amdgcn_readlane((int)(unsigned)k, 63);
  unsigned mhi =
      (unsigned)__builtin_amdgcn_readlane((int)(unsigned)(k >> 32), 63);
  return ((unsigned long long)mhi << 32) | mlo;
}

// ---------------- kernel A: fused cue-norm + sims + patch inv-norms -------
// grid = (N/RPB, B), 256 threads = 4 waves. R8 structure (cues in LDS,
// 1-deep ping-pong prefetch) with the dot products forced onto
// v_pk_fma_f32 (2 FMAs/issue) -> per-row issue count ~halved.
__global__ __launch_bounds__(256, 4) void sims_kernel(
    const float* __restrict__ patches, const float* __restrict__ cue,
    float* __restrict__ sims, float* __restrict__ invn) {
  int b = blockIdx.y;
  int row0 = blockIdx.x * RPB;
  int wid = threadIdx.x >> 6;
  int lane = threadIdx.x & 63;

  __shared__ float cue_lds[KK * DD];  // 20 KB, normalized cues

  const f32x4* pb = (const f32x4*)(patches + (size_t)b * NN * DD);

  // prologue: issue row-0 loads immediately (don't wait for cue norm)
  const f32x4* pc = pb + (size_t)(row0 + wid) * 256;
  f32x4 cur0 = pc[lane], cur1 = pc[64 + lane], cur2 = pc[128 + lane],
        cur3 = pc[192 + lane];

  // cooperative cue normalize: wave w handles k = w, w+4 (wave0 gets k=4)
  for (int k = wid; k < KK; k += 4) {
    const f32x4* cb = (const f32x4*)(cue + ((size_t)b * KK + k) * DD);
    f32x4 v[4];
#pragma unroll
    for (int j = 0; j < 4; ++j) v[j] = cb[j * 64 + lane];
    float s = 0.f;
#pragma unroll
    for (int j = 0; j < 4; ++j)
      s += v[j].x * v[j].x + v[j].y * v[j].y + v[j].z * v[j].z +
           v[j].w * v[j].w;
    s = wave_sum63(s);
    s = __int_as_float(__builtin_amdgcn_readlane(__float_as_int(s), 63));
    float inv = 1.0f / fmaxf(sqrtf(s), EPSV);
#pragma unroll
    for (int j = 0; j < 4; ++j) {
      f32x4 o;
      o.x = v[j].x * inv; o.y = v[j].y * inv;
      o.z = v[j].z * inv; o.w = v[j].w * inv;
      *(f32x4*)&cue_lds[k * DD + j * 256 + lane * 4] = o;
    }
  }
  __syncthreads();

#pragma unroll 2
  for (int i = 0; i < RPB / 4; ++i) {
    int r = wid + 4 * i;   // row within block
    int row = row0 + r;    // row within batch
    // prefetch next row (last iter re-loads current: harmless L2 hit)
    int rn = (i < RPB / 4 - 1) ? (r + 4) : r;
    const f32x4* pn = pb + (size_t)(row0 + rn) * 256;
    f32x4 n0 = pn[lane], n1 = pn[64 + lane], n2 = pn[128 + lane],
          n3 = pn[192 + lane];

    f32x2 a0 = {0.f, 0.f}, a1 = {0.f, 0.f}, a2 = {0.f, 0.f},
          a3 = {0.f, 0.f}, a4 = {0.f, 0.f}, an = {0.f, 0.f};
#pragma unroll
    for (int j = 0; j < 4; ++j) {
      f32x4 p = (j == 0) ? cur0 : (j == 1) ? cur1 : (j == 2) ? cur2 : cur3;
      f32x2 plo = {p.x, p.y}, phi = {p.z, p.w};
      an = pk_fma(plo, plo, an);
      an = pk_fma(phi, phi, an);
      const float* cl = &cue_lds[j * 256 + lane * 4];
      f32x4 c0 = *(const f32x4*)(cl + 0 * DD);
      f32x4 c1 = *(const f32x4*)(cl + 1 * DD);
      f32x4 c2 = *(const f32x4*)(cl + 2 * DD);
      f32x4 c3 = *(const f32x4*)(cl + 3 * DD);
      f32x4 c4 = *(const f32x4*)(cl + 4 * DD);
      a0 = pk_fma(plo, (f32x2){c0.x, c0.y}, a0);
      a0 = pk_fma(phi, (f32x2){c0.z, c0.w}, a0);
      a1 = pk_fma(plo, (f32x2){c1.x, c1.y}, a1);
      a1 = pk_fma(phi, (f32x2){c1.z, c1.w}, a1);
      a2 = pk_fma(plo, (f32x2){c2.x, c2.y}, a2);
      a2 = pk_fma(phi, (f32x2){c2.z, c2.w}, a2);
      a3 = pk_fma(plo, (f32x2){c3.x, c3.y}, a3);
      a3 = pk_fma(phi, (f32x2){c3.z, c3.w}, a3);
      a4 = pk_fma(plo, (f32x2){c4.x, c4.y}, a4);
      a4 = pk_fma(phi, (f32x2){c4.z, c4.w}, a4);
    }
    float nr = an.x + an.y;
    float acc0 = a0.x + a0.y, acc1 = a1.x + a1.y, acc2 = a2.x + a2.y,
          acc3 = a3.x + a3.y, acc4 = a4.x + a4.y;
    // 6 independent DPP reduce chains; results land in lane 63
    nr = wave_sum63(nr);
    acc0 = wave_sum63(acc0);
    acc1 = wave_sum63(acc1);
    acc2 = wave_sum63(acc2);
    acc3 = wave_sum63(acc3);
    acc4 = wave_sum63(acc4);
    if (lane == 63) {
      float inv = 1.0f / fmaxf(sqrtf(nr), EPSV);
      invn[b * NN + row] = inv;
      sims[((size_t)b * KK + 0) * NN + row] = acc0 * inv;
      sims[((size_t)b * KK + 1) * NN + row] = acc1 * inv;
      sims[((size_t)b * KK + 2) * NN + row] = acc2 * inv;
      sims[((size_t)b * KK + 3) * NN + row] = acc3 * inv;
      sims[((size_t)b * KK + 4) * NN + row] = acc4 * inv;
    }
    cur0 = n0; cur1 = n1; cur2 = n2; cur3 = n3;
  }
}

// ---------------- kernel B: register top-9 + gather-mean ----------------
__global__ __launch_bounds__(256) void topk_gather_kernel(
    const float* __restrict__ patches, const float* __restrict__ sims,
    const float* __restrict__ invn, float* __restrict__ out) {
  int bk = blockIdx.x;  // 0..B*K
  int b = bk / KK;
  int wid = threadIdx.x >> 6, lane = threadIdx.x & 63;

  unsigned long long key[16];
  const float4* srow = (const float4*)(sims + (size_t)bk * NN);
#pragma unroll
  for (int j = 0; j < 4; ++j) {
    float4 v = srow[j * 256 + threadIdx.x];
    int base = 4 * (j * 256 + threadIdx.x);
    float vv[4] = {v.x, v.y, v.z, v.w};
#pragma unroll
    for (int e = 0; e < 4; ++e) {
      unsigned u = __float_as_uint(vv[e]);
      u = (u & 0x80000000u) ? ~u : (u | 0x80000000u);
      key[j * 4 + e] =
          ((unsigned long long)u << 32) | (unsigned)(~(base + e));
    }
  }

  __shared__ unsigned long long cand[4 * TOPK];
  __shared__ int sel_idx[TOPK];
  __shared__ float sel_inv[TOPK];

#pragma unroll
  for (int it = 0; it < TOPK; ++it) {
    unsigned long long m = key[0];
#pragma unroll
    for (int j = 1; j < 16; ++j) m = key[j] > m ? key[j] : m;
    m = wave_max_u64(m);  // uniform across the wave
    if (lane == 0) cand[wid * TOPK + it] = m;
#pragma unroll
    for (int j = 0; j < 16; ++j)
      if (key[j] == m) key[j] = 0ull;
  }
  __syncthreads();

  if (wid == 0) {
    unsigned long long k2 = (lane < 4 * TOPK) ? cand[lane] : 0ull;
#pragma unroll
    for (int it = 0; it < TOPK; ++it) {
      unsigned long long m = wave_max_u64(k2);
      if (k2 == m) k2 = 0ull;
      if (lane == 0) {
        int idx = (int)(~(unsigned)(m & 0xFFFFFFFFu));
        sel_idx[it] = idx;
        sel_inv[it] = invn[b * NN + idx];
      }
    }
  }
  __syncthreads();

  const float4* pb = (const float4*)(patches + (size_t)b * NN * DD);
  float4 acc; acc.x = acc.y = acc.z = acc.w = 0.f;
#pragma unroll
  for (int it = 0; it < TOPK; ++it) {
    float inv = sel_inv[it];
    float4 p = pb[(size_t)sel_idx[it] * 256 + threadIdx.x];
    acc.x += p.x * inv; acc.y += p.y * inv;
    acc.z += p.z * inv; acc.w += p.w * inv;
  }
  const float inv9 = 1.0f / 9.0f;
  float4 o;
  o.x = acc.x * inv9; o.y = acc.y * inv9;
  o.z = acc.z * inv9; o.w = acc.w * inv9;
  ((float4*)(out + (size_t)bk * DD))[threadIdx.x] = o;
}

extern "C" void kernel_launch(void* const* d_in, const int* in_sizes, int n_in,
                              void* d_out, int out_size, void* d_ws, size_t ws_size,
                              hipStream_t stream) {
  const float* cue = (const float*)d_in[0];      // (B, K, D) f32
  const float* patches = (const float*)d_in[1];  // (B, N, D) f32
  float* out = (float*)d_out;                    // (B, K, D) f32

  float* invn = (float*)d_ws;                    // B*N   = 65536
  float* sims = invn + (size_t)BB * NN;          // B*K*N = 327680

  dim3 g2(NN / RPB, BB);
  sims_kernel<<<g2, 256, 0, stream>>>(patches, cue, sims, invn);
  topk_gather_kernel<<<BB * KK, 256, 0, stream>>>(patches, sims, invn, out);
}